// Round 9
// baseline (117.073 us; speedup 1.0000x reference)
//
#include <hip/hip_runtime.h>

typedef float f32x2 __attribute__((ext_vector_type(2)));
typedef float f32x4 __attribute__((ext_vector_type(4)));

#define BB 4
#define NN 8192
#define NPTS (BB * NN)                  // 32768 per cloud
#define TILE 256
#define RI 8                            // self points per thread
#define SELF_PER_BLOCK (TILE * RI)      // 2048
#define STILES (NN / SELF_PER_BLOCK)    // 4
#define JSPLIT 32                       // j-windows per (b,dir)
#define JRANGE (NN / JSPLIT)            // 256 j per window
#define JPAIRS (JRANGE / 2)             // 128 staged pairs (4 KB LDS)
#define RBLOCKS 64                      // reduce-kernel blocks

// Identical structure to round 8; ONLY change: depth-1 software pipeline on
// the LDS q-feed (prefetch pair kp+1 into registers before computing kp), so
// the ~120-cyc ds_read latency overlaps the 128-cyc VALU body instead of
// serializing with it.
__global__ __launch_bounds__(TILE) void chamfer_main(
    const float* __restrict__ p1, const float* __restrict__ p2,
    float* __restrict__ pm)
{
    const int bz  = blockIdx.y;             // 0..7
    const int b   = bz >> 1;
    const int dir = bz & 1;                 // 0: self=p1, other=p2
    const int stile = blockIdx.x >> 5;      // 0..3   (JSPLIT=32)
    const int js    = blockIdx.x & 31;      // 0..31

    const float* selfp  = dir ? p2 : p1;
    const float* otherp = dir ? p1 : p2;

    // ---- Stage j-window pair-packed into LDS ----
    // soA[jp] = (-2x0,-2x1,-2y0,-2y1)  soB[jp] = (-2z0,-2z1,|q0|^2,|q1|^2)
    __shared__ f32x4 soA[JPAIRS];
    __shared__ f32x4 soB[JPAIRS];
    if (threadIdx.x < JPAIRS) {
        const int t = threadIdx.x;
        const float2* src = reinterpret_cast<const float2*>(
            otherp + ((size_t)b * NN + (size_t)js * JRANGE) * 3);
        const float2 u = src[3*t], v = src[3*t+1], w = src[3*t+2];
        const float x0=u.x, y0=u.y, z0=v.x, x1=v.y, y1=w.x, z1=w.y;
        soA[t] = f32x4{-2.f*x0, -2.f*x1, -2.f*y0, -2.f*y1};
        soB[t] = f32x4{-2.f*z0, -2.f*z1,
                       fmaf(x0,x0,fmaf(y0,y0,z0*z0)),
                       fmaf(x1,x1,fmaf(y1,y1,z1*z1))};
    }

    // ---- Self points (RI per thread, strided TILE) ----
    const int i0 = stile * SELF_PER_BLOCK + threadIdx.x;
    float ax[RI], ay[RI], az[RI];
    #pragma unroll
    for (int s = 0; s < RI; ++s) {
        const float* sp = selfp + ((size_t)b * NN + i0 + s * TILE) * 3;
        ax[s] = sp[0]; ay[s] = sp[1]; az[s] = sp[2];
    }
    __syncthreads();

    // ---- Main scan: 128 pair-iters, depth-1 pipelined LDS feed ----
    f32x2 m[RI];
    #pragma unroll
    for (int s = 0; s < RI; ++s) m[s] = f32x2{3.4e38f, 3.4e38f};

#define CHAMFER_BODY(Aq, Bq)                                                   \
    do {                                                                       \
        const f32x2 qx = (Aq).xy, qy = (Aq).zw, qz = (Bq).xy, qw = (Bq).zw;    \
        _Pragma("unroll")                                                      \
        for (int s = 0; s < RI; ++s) {                                         \
            const f32x2 v = __builtin_elementwise_fma(f32x2{ax[s],ax[s]}, qx,  \
                            __builtin_elementwise_fma(f32x2{ay[s],ay[s]}, qy,  \
                            __builtin_elementwise_fma(f32x2{az[s],az[s]}, qz,  \
                                                      qw)));                   \
            m[s] = __builtin_elementwise_min(m[s], v);                         \
        }                                                                      \
    } while (0)

    f32x4 A0 = soA[0], B0 = soB[0];
    #pragma unroll 2
    for (int kp = 0; kp < JPAIRS - 1; ++kp) {
        const f32x4 A1 = soA[kp + 1];   // issued before the 128-cyc body below
        const f32x4 B1 = soB[kp + 1];
        CHAMFER_BODY(A0, B0);
        A0 = A1; B0 = B1;
    }
    CHAMFER_BODY(A0, B0);
#undef CHAMFER_BODY

    // ---- Epilogue: +|a|^2, clamp, plain store (no atomics) ----
    float* row = pm + ((size_t)bz * JSPLIT + js) * NN + i0;
    #pragma unroll
    for (int s = 0; s < RI; ++s) {
        const float a2 = fmaf(ax[s],ax[s], fmaf(ay[s],ay[s], az[s]*az[s]));
        row[s * TILE] = fmaxf(fminf(m[s].x, m[s].y) + a2, 0.f);
    }
}

// Reduce 1: per (bz,i) min over the JSPLIT window-partials, then block sums.
__global__ __launch_bounds__(1024) void chamfer_reduce(
    const float* __restrict__ pm, float* __restrict__ bsums)
{
    const int sIdx = blockIdx.x * 1024 + threadIdx.x;   // 0..65535
    const int bz = sIdx >> 13;
    const int i  = sIdx & (NN - 1);
    const float* base = pm + (size_t)bz * JSPLIT * NN + i;
    float mn = base[0];
    #pragma unroll
    for (int js = 1; js < JSPLIT; ++js)
        mn = fminf(mn, base[(size_t)js * NN]);          // coalesced per js

    float ssum = mn;
    #pragma unroll
    for (int off = 32; off; off >>= 1) ssum += __shfl_down(ssum, off);

    __shared__ float wsum[16];
    const int lane = threadIdx.x & 63, wid = threadIdx.x >> 6;
    if (lane == 0) wsum[wid] = ssum;
    __syncthreads();
    if (threadIdx.x == 0) {
        float t = 0.f;
        #pragma unroll
        for (int w = 0; w < 16; ++w) t += wsum[w];
        bsums[blockIdx.x] = t;
    }
}

// Reduce 2: one wave sums the RBLOCKS block sums. mean(d12)+mean(d21)
// = sum(all 2*B*N mins)/(B*N) since N == M.
__global__ __launch_bounds__(64) void chamfer_final(
    const float* __restrict__ bsums, float* __restrict__ out)
{
    float s = bsums[threadIdx.x];
    #pragma unroll
    for (int off = 32; off; off >>= 1) s += __shfl_down(s, off);
    if (threadIdx.x == 0) out[0] = s * (1.f / (float)NPTS);
}

extern "C" void kernel_launch(void* const* d_in, const int* in_sizes, int n_in,
                              void* d_out, int out_size, void* d_ws, size_t ws_size,
                              hipStream_t stream)
{
    const float* p1 = (const float*)d_in[0];
    const float* p2 = (const float*)d_in[1];
    float* pm    = (float*)d_ws;                         // 8*32*8192 f32 = 8 MB
    float* bsums = pm + (size_t)2 * BB * JSPLIT * NN;    // + 64 floats
    float* out   = (float*)d_out;

    dim3 grid(STILES * JSPLIT, 2 * BB);                  // 128 x 8 = 1024 blocks
    chamfer_main<<<grid, TILE, 0, stream>>>(p1, p2, pm);
    chamfer_reduce<<<RBLOCKS, 1024, 0, stream>>>(pm, bsums);
    chamfer_final<<<1, 64, 0, stream>>>(bsums, out);
}